// Round 16
// baseline (56.443 us; speedup 1.0000x reference)
//
#include <hip/hip_runtime.h>

#define NPTS   8192
#define BATCH  32
#define CIN    64
#define COUT   64
#define RANKK  16
#define ROWS   (BATCH * CIN)   // 2048 = BATCH*COUT too
#define KB_SPLIT 16            // outer K split (Sp segments)

typedef _Float16 f16;
typedef _Float16 f16x8 __attribute__((ext_vector_type(8)));
typedef float    f32x4 __attribute__((ext_vector_type(4)));

__device__ __forceinline__ void gload16(const void* g, void* l) {
  __builtin_amdgcn_global_load_lds(
      (const __attribute__((address_space(1))) void*)g,
      (__attribute__((address_space(3))) void*)l, 16, 0, 0);
}

// ---------------------------------------------------------------------------
// Kernel 1: build cos/sin tables in f16, using T[c][n+N/2] = (-1)^k T[c][n].
//   T [c][n]  c<64: cos(2*pi*c*n/N), c>=64: sin(2*pi*(c-64)*n/N)
//   Tt[n][c]  transpose of T
// (R15-proven, unchanged)
// ---------------------------------------------------------------------------
__global__ __launch_bounds__(256) void build_tables(f16* __restrict__ T,
                                                    f16* __restrict__ Tt) {
  __shared__ f16 tile[128][18];  // pad to break transpose bank conflicts
  const int n0 = blockIdx.x * 16;          // n0 in [0,4096)
  const int t = threadIdx.x;
#pragma unroll
  for (int j = 0; j < 8; ++j) {
    int flat = t + 256 * j;          // 0..2047
    int c = flat >> 4, dn = flat & 15;
    int k = c & 63, n = n0 + dn;
    int m = (k * n) & (NPTS - 1);    // arg reduction: k*n mod N
    float ang = (float)m * (6.28318530717958647692f / (float)NPTS);
    float sv, cv;
    sincosf(ang, &sv, &cv);
    tile[c][dn] = (f16)((c < 64) ? cv : sv);
  }
  __syncthreads();
#pragma unroll
  for (int j = 0; j < 8; ++j) {      // write T[c][n] + mirror (coalesced in n)
    int flat = t + 256 * j;
    int c = flat >> 4, dn = flat & 15;
    f16 v = tile[c][dn];
    f16 vm = ((c & 1) ? (f16)(-v) : v);          // (-1)^k, k = c&63
    T[(size_t)c * NPTS + n0 + dn] = v;
    T[(size_t)c * NPTS + n0 + dn + NPTS / 2] = vm;
  }
#pragma unroll
  for (int j = 0; j < 8; ++j) {      // write Tt[n][c] + mirror (coalesced in c)
    int flat = t + 256 * j;
    int dn = flat >> 7, c = flat & 127;
    f16 v = tile[c][dn];
    f16 vm = ((c & 1) ? (f16)(-v) : v);
    Tt[(size_t)(n0 + dn) * 128 + c] = v;
    Tt[(size_t)(n0 + dn + NPTS / 2) * 128 + c] = vm;
  }
}

// ---------------------------------------------------------------------------
// Kernel 2: forward "DFT" GEMM, LDS-staged, depth-3 async pipeline.
//   Sp[kb][row][c] = sum_{n in K-block kb} x[row][n] * T[c][n]   (f16 partials)
// Grid = 32 row-blocks(64 rows) x 16 kb. Block: 4 waves, C-tile 64x128,
// K-range 512 in 16 steps of 32. Staging: global_load_lds w16, 4 LDS slots,
// stage kt+3 ahead, counted vmcnt(8) (tail 4 -> 0). Same proven STAGE/COMPUTE
// bodies and XOR-swizzle maps as R7/R13/R15.
// ---------------------------------------------------------------------------
__global__ __launch_bounds__(256) void fwd_dft(const float* __restrict__ x,
                                               const f16* __restrict__ T,
                                               f16* __restrict__ Sp) {
  __shared__ __align__(16) char lds[4 * 16384];  // 4 slots x (8K x + 8K T)
  const int t    = threadIdx.x;
  const int w    = t >> 6;
  const int lane = t & 63;
  const int rl = lane & 15, hi = lane >> 4;
  const int kb = blockIdx.x & (KB_SPLIT - 1);
  const int r0 = (blockIdx.x >> 4) * 64;       // row-block base
  const int k0 = kb * (NPTS / KB_SPLIT);       // 512-wide K range

  // dest chunk -> pre-swizzled global source (involution: c^row-bits)
  const int xc0 = t, xc1 = t + 256;            // x chunks (row=c>>3, cc=c&7)
  const int tc0 = t, tc1 = t + 256;            // T chunks (row=c>>2, cc=c&3)
  const int xr0_ = xc0 >> 3, xr1_ = xc1 >> 3;
  const int tr0_ = tc0 >> 2, tr1_ = tc1 >> 2;
  const int xo0 = ((xc0 & 7) ^ (xr0_ & 7)) << 2;  // float offset in 32-col step
  const int xo1 = ((xc1 & 7) ^ (xr1_ & 7)) << 2;
  const int to0 = ((tc0 & 3) ^ (tr0_ & 3)) << 3;  // f16 offset
  const int to1 = ((tc1 & 3) ^ (tr1_ & 3)) << 3;
  const float* xs0 = x + (size_t)(r0 + xr0_) * NPTS + k0 + xo0;
  const float* xs1 = x + (size_t)(r0 + xr1_) * NPTS + k0 + xo1;
  const f16*   ts0 = T + (size_t)tr0_ * NPTS + k0 + to0;
  const f16*   ts1 = T + (size_t)tr1_ * NPTS + k0 + to1;
  const int wu = w * 64 * 16;                  // wave-uniform LDS byte base

  auto STAGE = [&](int kt, int slot) {
    char* xb = lds + slot * 16384;
    char* tb = xb + 8192;
    const int kk = kt * 32;
    gload16(xs0 + kk, xb + wu);
    gload16(xs1 + kk, xb + 4096 + wu);
    gload16(ts0 + kk, tb + wu);
    gload16(ts1 + kk, tb + 4096 + wu);
  };

  f32x4 acc[8];
#pragma unroll
  for (int i = 0; i < 8; ++i) acc[i] = (f32x4){0.f, 0.f, 0.f, 0.f};

  // swizzled read offsets (lane-constant across kt)
  const int axr = w * 16 + rl;  // x_tile row for this lane's A fragment
  const int ad0 = (axr * 8 + ((2 * hi) ^ (axr & 7))) * 16;
  const int ad1 = (axr * 8 + ((2 * hi + 1) ^ (axr & 7))) * 16;
  int bd[8];
#pragma unroll
  for (int ct = 0; ct < 8; ++ct) {
    int trow = ct * 16 + rl;
    bd[ct] = (trow * 4 + (hi ^ (trow & 3))) * 16;
  }

  auto COMPUTE = [&](int slot) {
    char* xb = lds + slot * 16384;
    char* tb = xb + 8192;
    f32x4 a0 = *(const f32x4*)(xb + ad0);
    f32x4 a1 = *(const f32x4*)(xb + ad1);
    f16x8 af;
#pragma unroll
    for (int j = 0; j < 4; ++j) { af[j] = (f16)a0[j]; af[4 + j] = (f16)a1[j]; }
#pragma unroll
    for (int ct = 0; ct < 8; ++ct) {
      f16x8 bf = *(const f16x8*)(tb + bd[ct]);
      acc[ct] = __builtin_amdgcn_mfma_f32_16x16x32_f16(af, bf, acc[ct], 0, 0, 0);
    }
  };

  STAGE(0, 0);
  STAGE(1, 1);
  STAGE(2, 2);
  asm volatile("s_waitcnt vmcnt(8)" ::: "memory");  // slot0 landed; 1,2 in flight
  __builtin_amdgcn_s_barrier();

  for (int kt = 0; kt < 16; ++kt) {
    if (kt + 3 < 16) STAGE(kt + 3, (kt + 3) & 3);
    COMPUTE(kt & 3);
    if (kt < 15) {
      // need slot kt+1 landed; outstanding after = 4 x |{kt+2,kt+3} ∩ <=15|
      if (kt <= 12)
        asm volatile("s_waitcnt vmcnt(8)" ::: "memory");
      else if (kt == 13)
        asm volatile("s_waitcnt vmcnt(4)" ::: "memory");
      else
        asm volatile("s_waitcnt vmcnt(0)" ::: "memory");
      __builtin_amdgcn_s_barrier();
    }
  }

  // epilogue: wave w owns rows r0+w*16..+16 (C/D map: row=hi*4+i, col=ct*16+rl)
  f16* out = Sp + ((size_t)kb * ROWS + r0 + w * 16) * 128;
#pragma unroll
  for (int ct = 0; ct < 8; ++ct)
#pragma unroll
    for (int i = 0; i < 4; ++i)
      out[(hi * 4 + i) * 128 + ct * 16 + rl] = (f16)acc[ct][i];
}

// ---------------------------------------------------------------------------
// Kernel 3: FUSED split-K reduce + rank-factored mix -> Qh (f16).
// Grid = 32 (one block per batch), 1024 threads (16 waves). Sp read ONCE.
//   S[i][k] complex (Srs/Sis f32 in LDS)  <- sum of 16 f16 segments
//   P[k][r] = s[r] * sum_i (sr - i*si)[i,k] * (ur + i*ui)[i,r]   (folded Sv)
//   Q[o][k] = sum_r P[k,r] * (vr + i*vi)[r,o]
//   Qh[b*64+o][k] = qr*ck/N ; Qh[..][64+k] = -qi*ck/N
// Identical algebra to reduce_k+mix3 (associativity differs, f32 accum).
// ---------------------------------------------------------------------------
__global__ __launch_bounds__(1024) void mix_rank(const f16* __restrict__ Sp,
                                                 const float* __restrict__ Ur,
                                                 const float* __restrict__ Ui,
                                                 const float* __restrict__ Vr,
                                                 const float* __restrict__ Vi,
                                                 const float* __restrict__ Sv,
                                                 f16* __restrict__ Qh) {
  __shared__ float Srs[64][64], Sis[64][64];   // 32 KiB
  __shared__ float Pr[64][16], Pi[64][16];     // 8 KiB
  const int b = blockIdx.x;
  const int t = threadIdx.x;                   // 0..1023

  // ---- phase 1: reduce 16 f16 segments; chunk t = row i=t>>4, cols (t&15)*8
  {
    float accs[8];
#pragma unroll
    for (int e = 0; e < 8; ++e) accs[e] = 0.f;
    const f16* base = Sp + (size_t)b * 64 * 128 + (size_t)t * 8;
    for (int seg = 0; seg < KB_SPLIT; ++seg) {
      f16x8 v = *(const f16x8*)(base + (size_t)seg * (ROWS * 128));
#pragma unroll
      for (int e = 0; e < 8; ++e) accs[e] += (float)v[e];
    }
    int i = t >> 4, cc = (t & 15) * 8;
    float* dst = (cc < 64) ? &Srs[i][cc] : &Sis[i][cc - 64];
#pragma unroll
    for (int e = 0; e < 8; ++e) dst[e] = accs[e];
  }
  __syncthreads();

  // ---- phase 2: P[k][r], one (k,r) per thread: k=t>>4, r=t&15
  {
    const int k = t >> 4, r = t & 15;
    float pr = 0.f, pi = 0.f;
#pragma unroll 8
    for (int i = 0; i < 64; ++i) {
      float sr = Srs[i][k], si = Sis[i][k];       // LDS broadcast
      float ur = Ur[i * RANKK + r], ui = Ui[i * RANKK + r];
      pr += sr * ur + si * ui;
      pi += sr * ui - si * ur;
    }
    float s = Sv[r];
    Pr[k][r] = pr * s;
    Pi[k][r] = pi * s;
  }
  __syncthreads();

  // ---- phase 3: Q[o][k] for o=t&63, k = (t>>6)*4 + j
  {
    const int o = t & 63, kq = t >> 6;            // kq 0..15
    f16* qrow = Qh + ((size_t)(b * 64 + o)) * 128;
#pragma unroll
    for (int j = 0; j < 4; ++j) {
      int k = kq * 4 + j;
      float qr = 0.f, qi = 0.f;
#pragma unroll
      for (int r = 0; r < RANKK; ++r) {
        float pr = Pr[k][r], pi = Pi[k][r];       // wave-uniform broadcast
        float vr = Vr[r * COUT + o], vi = Vi[r * COUT + o];
        qr += pr * vr - pi * vi;
        qi += pr * vi + pi * vr;
      }
      float sk = (k == 0 ? 1.0f : 2.0f) / (float)NPTS;
      qrow[k]      = (f16)(qr * sk);
      qrow[64 + k] = (f16)(-qi * sk);
    }
  }
}

// ---------------------------------------------------------------------------
// Kernel 4: inverse GEMM, block-tiled, plain reg-staged LDS (no swizzle).
//   y[row][n] = sum_c Qh[row][c] * Tt[n][c]
// (R9/R13/R15-proven PASS structure, unchanged)
// ---------------------------------------------------------------------------
__global__ __launch_bounds__(256) void inv_dft(const f16* __restrict__ Qh,
                                               const f16* __restrict__ Tt,
                                               float* __restrict__ y) {
  __shared__ f16   Bt[64][136];    // 64 n-rows x 128 k  (+8 f16 pad)
  __shared__ float Tr[4][16][68];  // per-wave store transpose (+4 pad)
  const int t = threadIdx.x, w = t >> 6, lane = t & 63;
  const int rl = lane & 15, hi = lane >> 4;
  const int nb = blockIdx.x & 127;   // n-block (64 wide)
  const int rb = blockIdx.x >> 7;    // row-block (64 rows)
  const int n0 = nb * 64, r0 = rb * 64;

  // stage B tile: 1024 chunks of 8 f16; thread t takes chunks t+256j (coalesced)
  f16x8 stg[4];
#pragma unroll
  for (int j = 0; j < 4; ++j) {
    int d = j * 256 + t, row = d >> 4, q = d & 15;
    stg[j] = *(const f16x8*)(Tt + (size_t)(n0 + row) * 128 + q * 8);
  }
  // A fragments: rows r0 + w*16 + rl, k = 32*ksv + 8*hi (+j)
  const f16* qrow = Qh + (size_t)(r0 + w * 16 + rl) * 128 + 8 * hi;
  f16x8 af[4];
#pragma unroll
  for (int ksv = 0; ksv < 4; ++ksv) af[ksv] = *(const f16x8*)(qrow + ksv * 32);
#pragma unroll
  for (int j = 0; j < 4; ++j) {
    int d = j * 256 + t, row = d >> 4, q = d & 15;
    *(f16x8*)(&Bt[row][q * 8]) = stg[j];
  }
  __syncthreads();

  f32x4 acc[4];
#pragma unroll
  for (int i = 0; i < 4; ++i) acc[i] = (f32x4){0.f, 0.f, 0.f, 0.f};

#pragma unroll
  for (int ksv = 0; ksv < 4; ++ksv)
#pragma unroll
    for (int s = 0; s < 4; ++s) {
      f16x8 bf = *(const f16x8*)(&Bt[s * 16 + rl][(ksv * 4 + hi) * 8]);
      acc[s] = __builtin_amdgcn_mfma_f32_16x16x32_f16(af[ksv], bf, acc[s], 0, 0, 0);
    }

  // epilogue: per-wave transpose in padded LDS, then coalesced float4 stores.
#pragma unroll
  for (int s = 0; s < 4; ++s)
#pragma unroll
    for (int i = 0; i < 4; ++i)
      Tr[w][hi * 4 + i][s * 16 + rl] = acc[s][i];
#pragma unroll
  for (int p = 0; p < 4; ++p) {
    int r = p * 4 + hi;
    f32x4 v = *(const f32x4*)(&Tr[w][r][rl * 4]);
    *(f32x4*)(y + (size_t)(r0 + w * 16 + r) * NPTS + n0 + rl * 4) = v;
  }
}

// ---------------------------------------------------------------------------
extern "C" void kernel_launch(void* const* d_in, const int* in_sizes, int n_in,
                              void* d_out, int out_size, void* d_ws, size_t ws_size,
                              hipStream_t stream) {
  const float* x  = (const float*)d_in[0];
  const float* Ur = (const float*)d_in[1];
  const float* Ui = (const float*)d_in[2];
  const float* Vr = (const float*)d_in[3];
  const float* Vi = (const float*)d_in[4];
  const float* Sv = (const float*)d_in[5];
  float* y = (float*)d_out;
  char* ws = (char*)d_ws;

  // workspace layout (12.5 MiB total):
  f16*   T    = (f16*)ws;                              // 2 MiB
  f16*   Tt   = (f16*)(ws + (2u << 20));               // 2 MiB
  f16*   Sp   = (f16*)(ws + (4u << 20));               // KB_SPLIT * 512 KiB = 8 MiB
  f16*   Qh   = (f16*)(ws + (4u << 20) +
                       (size_t)KB_SPLIT * ROWS * 128 * 2);  // 512 KiB

  build_tables<<<NPTS / 32, 256, 0, stream>>>(T, Tt);
  fwd_dft<<<(ROWS / 64) * KB_SPLIT, 256, 0, stream>>>(x, T, Sp);
  mix_rank<<<BATCH, 1024, 0, stream>>>(Sp, Ur, Ui, Vr, Vi, Sv, Qh);
  inv_dft<<<(ROWS / 64) * (NPTS / 64), 256, 0, stream>>>(Qh, Tt, y);
}

// Round 17
// 50.195 us; speedup vs baseline: 1.1245x; 1.1245x over previous
//
#include <hip/hip_runtime.h>

#define NPTS   8192
#define BATCH  32
#define CIN    64
#define COUT   64
#define RANKK  16
#define ROWS   (BATCH * CIN)   // 2048 = BATCH*COUT too
#define KB_SPLIT 16            // outer K split (Sp segments)

typedef _Float16 f16;
typedef _Float16 f16x4 __attribute__((ext_vector_type(4)));
typedef _Float16 f16x8 __attribute__((ext_vector_type(8)));
typedef float    f32x4 __attribute__((ext_vector_type(4)));

__device__ __forceinline__ void gload16(const void* g, void* l) {
  __builtin_amdgcn_global_load_lds(
      (const __attribute__((address_space(1))) void*)g,
      (__attribute__((address_space(3))) void*)l, 16, 0, 0);
}

// ---------------------------------------------------------------------------
// Kernel 1: build cos/sin tables in f16, using T[c][n+N/2] = (-1)^k T[c][n].
//   T [c][n]  c<64: cos(2*pi*c*n/N), c>=64: sin(2*pi*(c-64)*n/N)
//   Tt[n][c]  transpose of T
// (R15-proven, unchanged)
// ---------------------------------------------------------------------------
__global__ __launch_bounds__(256) void build_tables(f16* __restrict__ T,
                                                    f16* __restrict__ Tt) {
  __shared__ f16 tile[128][18];  // pad to break transpose bank conflicts
  const int n0 = blockIdx.x * 16;          // n0 in [0,4096)
  const int t = threadIdx.x;
#pragma unroll
  for (int j = 0; j < 8; ++j) {
    int flat = t + 256 * j;          // 0..2047
    int c = flat >> 4, dn = flat & 15;
    int k = c & 63, n = n0 + dn;
    int m = (k * n) & (NPTS - 1);    // arg reduction: k*n mod N
    float ang = (float)m * (6.28318530717958647692f / (float)NPTS);
    float sv, cv;
    sincosf(ang, &sv, &cv);
    tile[c][dn] = (f16)((c < 64) ? cv : sv);
  }
  __syncthreads();
#pragma unroll
  for (int j = 0; j < 8; ++j) {      // write T[c][n] + mirror (coalesced in n)
    int flat = t + 256 * j;
    int c = flat >> 4, dn = flat & 15;
    f16 v = tile[c][dn];
    f16 vm = ((c & 1) ? (f16)(-v) : v);          // (-1)^k, k = c&63
    T[(size_t)c * NPTS + n0 + dn] = v;
    T[(size_t)c * NPTS + n0 + dn + NPTS / 2] = vm;
  }
#pragma unroll
  for (int j = 0; j < 8; ++j) {      // write Tt[n][c] + mirror (coalesced in c)
    int flat = t + 256 * j;
    int dn = flat >> 7, c = flat & 127;
    f16 v = tile[c][dn];
    f16 vm = ((c & 1) ? (f16)(-v) : v);
    Tt[(size_t)(n0 + dn) * 128 + c] = v;
    Tt[(size_t)(n0 + dn + NPTS / 2) * 128 + c] = vm;
  }
}

// ---------------------------------------------------------------------------
// Kernel 2: forward "DFT" GEMM, LDS-staged, depth-2 async pipeline, 8 WAVES.
//   Sp[kb][row][c] = sum_{n in K-block kb} x[row][n] * T[c][n]   (f16 partials)
// Grid = 32 row-blocks(64 rows) x 16 kb, 512 threads. Same 64x128 C-tile and
// 48 KiB LDS as R15 (3 blocks/CU) but 8 waves -> 24 waves/CU.
// Wave w: rows (w>>1)*16, cols (w&1)*64 (acc[4], 4 MFMA/K-step).
// Staging: exactly 2 gload16/thread (1 x-chunk + 1 T-chunk); vmcnt(2).
// Same XOR-swizzle maps as R7/R12/R15 (all refcheck-proven).
// ---------------------------------------------------------------------------
__global__ __launch_bounds__(512) void fwd_dft(const float* __restrict__ x,
                                               const f16* __restrict__ T,
                                               f16* __restrict__ Sp) {
  __shared__ __align__(16) char lds[3 * 16384];  // 3 slots x (8K x + 8K T)
  const int t    = threadIdx.x;                  // 0..511
  const int w    = t >> 6;                       // 0..7
  const int lane = t & 63;
  const int rl = lane & 15, hi = lane >> 4;
  const int kb = blockIdx.x & (KB_SPLIT - 1);
  const int r0 = (blockIdx.x >> 4) * 64;       // row-block base
  const int k0 = kb * (NPTS / KB_SPLIT);       // 512-wide K range

  // staging: one x chunk + one T chunk per thread, pre-swizzled global source
  const int xr_ = t >> 3;                        // x chunk row (0..63)
  const int xo_ = ((t & 7) ^ (xr_ & 7)) << 2;    // f32 offset in 32-col step
  const int tr_ = t >> 2;                        // T chunk row (0..127)
  const int to_ = ((t & 3) ^ (tr_ & 3)) << 3;    // f16 offset
  const float* xs0 = x + (size_t)(r0 + xr_) * NPTS + k0 + xo_;
  const f16*   ts0 = T + (size_t)tr_ * NPTS + k0 + to_;
  const int wu = w * 1024;                     // wave-uniform LDS byte base

  auto STAGE = [&](int kt, int slot) {
    char* xb = lds + slot * 16384;
    char* tb = xb + 8192;
    const int kk = kt * 32;
    gload16(xs0 + kk, xb + wu);
    gload16(ts0 + kk, tb + wu);
  };

  f32x4 acc[4];
#pragma unroll
  for (int i = 0; i < 4; ++i) acc[i] = (f32x4){0.f, 0.f, 0.f, 0.f};

  // swizzled read offsets (lane-constant across kt)
  const int h  = w >> 1;        // row quarter (0..3)
  const int cg = w & 1;         // col half (64 cols)
  const int axr = h * 16 + rl;  // x_tile row for this lane's A fragment
  const int ad0 = (axr * 8 + ((2 * hi) ^ (axr & 7))) * 16;
  const int ad1 = (axr * 8 + ((2 * hi + 1) ^ (axr & 7))) * 16;
  int bd[4];
#pragma unroll
  for (int s = 0; s < 4; ++s) {
    int trow = cg * 64 + s * 16 + rl;
    bd[s] = (trow * 4 + (hi ^ (trow & 3))) * 16;
  }

  auto COMPUTE = [&](int slot) {
    char* xb = lds + slot * 16384;
    char* tb = xb + 8192;
    f32x4 a0 = *(const f32x4*)(xb + ad0);
    f32x4 a1 = *(const f32x4*)(xb + ad1);
    f16x8 af;
#pragma unroll
    for (int j = 0; j < 4; ++j) { af[j] = (f16)a0[j]; af[4 + j] = (f16)a1[j]; }
#pragma unroll
    for (int s = 0; s < 4; ++s) {
      f16x8 bf = *(const f16x8*)(tb + bd[s]);
      acc[s] = __builtin_amdgcn_mfma_f32_16x16x32_f16(af, bf, acc[s], 0, 0, 0);
    }
  };

  STAGE(0, 0);
  STAGE(1, 1);
  asm volatile("s_waitcnt vmcnt(2)" ::: "memory");  // slot0 landed; slot1 in flight
  __builtin_amdgcn_s_barrier();

  int sc = 0, ss = 2;  // compute slot, stage slot
  for (int kt = 0; kt < 16; ++kt) {
    if (kt + 2 < 16) STAGE(kt + 2, ss);
    COMPUTE(sc);
    if (kt < 15) {
      if (kt + 2 < 16)
        asm volatile("s_waitcnt vmcnt(2)" ::: "memory");  // next slot landed
      else
        asm volatile("s_waitcnt vmcnt(0)" ::: "memory");  // drain final stage
      __builtin_amdgcn_s_barrier();
    }
    sc = (sc == 2) ? 0 : sc + 1;
    ss = (ss == 2) ? 0 : ss + 1;
  }

  // epilogue: wave owns rows r0+h*16..+16, cols cg*64..+64
  f16* out = Sp + ((size_t)kb * ROWS + r0 + h * 16) * 128 + cg * 64;
#pragma unroll
  for (int s = 0; s < 4; ++s)
#pragma unroll
    for (int i = 0; i < 4; ++i)
      out[(hi * 4 + i) * 128 + s * 16 + rl] = (f16)acc[s][i];
}

// ---------------------------------------------------------------------------
// Kernel 3a: split-K partial reduction, f16 in / f32 out, balanced vec widths.
//   Sred[row][c] = sum_seg Sp[seg][row][c]     (R15-proven, unchanged)
// ---------------------------------------------------------------------------
__global__ __launch_bounds__(256) void reduce_k(const f16* __restrict__ Sp,
                                                float* __restrict__ Sred) {
  const int idx = blockIdx.x * 256 + threadIdx.x;      // 0..65535 f16x4 idx
  const f16x4* src = (const f16x4*)Sp;
  f32x4 acc = (f32x4){0.f, 0.f, 0.f, 0.f};
#pragma unroll
  for (int s = 0; s < KB_SPLIT; ++s) {
    f16x4 v = src[(size_t)s * (ROWS * 128 / 4) + idx];
#pragma unroll
    for (int e = 0; e < 4; ++e) acc[e] += (float)v[e];
  }
  ((f32x4*)Sred)[idx] = acc;
}

// ---------------------------------------------------------------------------
// Kernel 3b: channel mix + scaling -> Qh (f16).  Grid: 32 batches x 16 o-groups.
// (R13/R15-proven structure, unchanged)
// ---------------------------------------------------------------------------
__global__ __launch_bounds__(256) void mix3(const float* __restrict__ Sred,
                                            const float* __restrict__ Ur,
                                            const float* __restrict__ Ui,
                                            const float* __restrict__ Vr,
                                            const float* __restrict__ Vi,
                                            const float* __restrict__ Sv,
                                            f16* __restrict__ Qh) {
  __shared__ float Srs[64][64], Sis[64][64];
  __shared__ float wr_s[64][4], wi_s[64][4];
  const int b  = blockIdx.x >> 4;
  const int og = blockIdx.x & 15;
  const int t  = threadIdx.x;

#pragma unroll
  for (int j = 0; j < 8; ++j) {
    int f4 = t + 256 * j;                // 0..2047 float4s
    int i = f4 >> 5, kc = (f4 & 31) * 4; // row i, col kc..kc+3
    f32x4 v = *(const f32x4*)(Sred + ((size_t)(b * 64 + i)) * 128 + kc);
    if (kc < 64) *(f32x4*)&Srs[i][kc] = v;
    else         *(f32x4*)&Sis[i][kc - 64] = v;
  }

  {
    int i = t >> 2, ol = t & 3, o = og * 4 + ol;
    float wr = 0.f, wi = 0.f;
#pragma unroll
    for (int r = 0; r < RANKK; ++r) {
      float ur = Ur[i * RANKK + r], ui = Ui[i * RANKK + r];
      float vr = Vr[r * COUT + o],  vi = Vi[r * COUT + o];
      float s = Sv[r];
      wr += s * (ur * vr - ui * vi);
      wi += s * (ur * vi + ui * vr);
    }
    wr_s[i][ol] = wr;
    wi_s[i][ol] = wi;
  }
  __syncthreads();

  const int ol = t >> 6, k = t & 63, o = og * 4 + ol;
  float qr = 0.f, qi = 0.f;
#pragma unroll 4
  for (int i = 0; i < 64; ++i) {
    float sr = Srs[i][k], si = Sis[i][k];     // stride-1 across lanes: conflict-free
    float wr = wr_s[i][ol], wi = wi_s[i][ol]; // wave-uniform broadcast
    qr += sr * wr + si * wi;
    qi += sr * wi - si * wr;
  }
  float sk = (k == 0 ? 1.0f : 2.0f) / (float)NPTS;  // c_k and both ortho 1/sqrt(N)
  f16* qrow = Qh + ((size_t)(b * 64 + o)) * 128;
  qrow[k]      = (f16)(qr * sk);
  qrow[64 + k] = (f16)(-qi * sk);
}

// ---------------------------------------------------------------------------
// Kernel 4: inverse GEMM, block-tiled, plain reg-staged LDS (no swizzle).
//   y[row][n] = sum_c Qh[row][c] * Tt[n][c]
// (R9/R13/R15-proven PASS structure, unchanged)
// ---------------------------------------------------------------------------
__global__ __launch_bounds__(256) void inv_dft(const f16* __restrict__ Qh,
                                               const f16* __restrict__ Tt,
                                               float* __restrict__ y) {
  __shared__ f16   Bt[64][136];    // 64 n-rows x 128 k  (+8 f16 pad)
  __shared__ float Tr[4][16][68];  // per-wave store transpose (+4 pad)
  const int t = threadIdx.x, w = t >> 6, lane = t & 63;
  const int rl = lane & 15, hi = lane >> 4;
  const int nb = blockIdx.x & 127;   // n-block (64 wide)
  const int rb = blockIdx.x >> 7;    // row-block (64 rows)
  const int n0 = nb * 64, r0 = rb * 64;

  // stage B tile: 1024 chunks of 8 f16; thread t takes chunks t+256j (coalesced)
  f16x8 stg[4];
#pragma unroll
  for (int j = 0; j < 4; ++j) {
    int d = j * 256 + t, row = d >> 4, q = d & 15;
    stg[j] = *(const f16x8*)(Tt + (size_t)(n0 + row) * 128 + q * 8);
  }
  // A fragments: rows r0 + w*16 + rl, k = 32*ksv + 8*hi (+j)
  const f16* qrow = Qh + (size_t)(r0 + w * 16 + rl) * 128 + 8 * hi;
  f16x8 af[4];
#pragma unroll
  for (int ksv = 0; ksv < 4; ++ksv) af[ksv] = *(const f16x8*)(qrow + ksv * 32);
#pragma unroll
  for (int j = 0; j < 4; ++j) {
    int d = j * 256 + t, row = d >> 4, q = d & 15;
    *(f16x8*)(&Bt[row][q * 8]) = stg[j];
  }
  __syncthreads();

  f32x4 acc[4];
#pragma unroll
  for (int i = 0; i < 4; ++i) acc[i] = (f32x4){0.f, 0.f, 0.f, 0.f};

#pragma unroll
  for (int ksv = 0; ksv < 4; ++ksv)
#pragma unroll
    for (int s = 0; s < 4; ++s) {
      f16x8 bf = *(const f16x8*)(&Bt[s * 16 + rl][(ksv * 4 + hi) * 8]);
      acc[s] = __builtin_amdgcn_mfma_f32_16x16x32_f16(af[ksv], bf, acc[s], 0, 0, 0);
    }

  // epilogue: per-wave transpose in padded LDS, then coalesced float4 stores.
#pragma unroll
  for (int s = 0; s < 4; ++s)
#pragma unroll
    for (int i = 0; i < 4; ++i)
      Tr[w][hi * 4 + i][s * 16 + rl] = acc[s][i];
#pragma unroll
  for (int p = 0; p < 4; ++p) {
    int r = p * 4 + hi;
    f32x4 v = *(const f32x4*)(&Tr[w][r][rl * 4]);
    *(f32x4*)(y + (size_t)(r0 + w * 16 + r) * NPTS + n0 + rl * 4) = v;
  }
}

// ---------------------------------------------------------------------------
extern "C" void kernel_launch(void* const* d_in, const int* in_sizes, int n_in,
                              void* d_out, int out_size, void* d_ws, size_t ws_size,
                              hipStream_t stream) {
  const float* x  = (const float*)d_in[0];
  const float* Ur = (const float*)d_in[1];
  const float* Ui = (const float*)d_in[2];
  const float* Vr = (const float*)d_in[3];
  const float* Vi = (const float*)d_in[4];
  const float* Sv = (const float*)d_in[5];
  float* y = (float*)d_out;
  char* ws = (char*)d_ws;

  // workspace layout (13.5 MiB total):
  f16*   T    = (f16*)ws;                              // 2 MiB
  f16*   Tt   = (f16*)(ws + (2u << 20));               // 2 MiB
  f16*   Sp   = (f16*)(ws + (4u << 20));               // KB_SPLIT * 512 KiB = 8 MiB
  char*  p    = ws + (4u << 20) + (size_t)KB_SPLIT * ROWS * 128 * 2;
  float* Sred = (float*)p;                             // 1 MiB
  f16*   Qh   = (f16*)(p + (size_t)ROWS * 128 * 4);    // 512 KiB

  build_tables<<<NPTS / 32, 256, 0, stream>>>(T, Tt);
  fwd_dft<<<(ROWS / 64) * KB_SPLIT, 512, 0, stream>>>(x, T, Sp);
  reduce_k<<<ROWS * 128 / 4 / 256, 256, 0, stream>>>(Sp, Sred);
  mix3<<<BATCH * 16, 256, 0, stream>>>(Sred, Ur, Ui, Vr, Vi, Sv, Qh);
  inv_dft<<<(ROWS / 64) * (NPTS / 64), 256, 0, stream>>>(Qh, Tt, y);
}

// Round 18
// 49.546 us; speedup vs baseline: 1.1392x; 1.0131x over previous
//
#include <hip/hip_runtime.h>

#define NPTS   8192
#define BATCH  32
#define CIN    64
#define COUT   64
#define RANKK  16
#define ROWS   (BATCH * CIN)   // 2048 = BATCH*COUT too
#define KB_SPLIT 16            // outer K split (Sp segments)

typedef _Float16 f16;
typedef _Float16 f16x4 __attribute__((ext_vector_type(4)));
typedef _Float16 f16x8 __attribute__((ext_vector_type(8)));
typedef float    f32x4 __attribute__((ext_vector_type(4)));

#define TWO_PI_OVER_N (6.28318530717958647692f / (float)NPTS)

__device__ __forceinline__ void gload16(const void* g, void* l) {
  __builtin_amdgcn_global_load_lds(
      (const __attribute__((address_space(1))) void*)g,
      (__attribute__((address_space(3))) void*)l, 16, 0, 0);
}

// table element (c, n):  c<64 -> cos(2*pi*c*n/N),  c>=64 -> sin(2*pi*(c-64)*n/N)
// sin(th) = cos(th - pi/2)  ->  integer phase m' = (freq*n + (c>=64)*6144) & 8191
__device__ __forceinline__ f16 trig_elem(int freq, int phase_off, int n) {
  int m = (freq * n + phase_off) & (NPTS - 1);
  return (f16)__cosf((float)m * TWO_PI_OVER_N);
}

// ---------------------------------------------------------------------------
// Kernel 1: forward "DFT" GEMM, LDS-staged x (async) + computed-in-LDS T.
//   Sp[kb][row][c] = sum_{n in K-block kb} x[row][n] * T[c][n]   (f16 partials)
// Grid = 32 row-blocks(64 rows) x 16 kb, 512 threads (8 waves, R17-proven).
// Per K-step: x 64x32 f32 (8 KiB) via 1 gload16/thread (vmcnt(1) counted);
// T 128x32 f16 (8 KiB) computed (8 cos/thread) + ds_write_b128.
// Same XOR-swizzle maps and slot rotation as R7/R15/R17 (refcheck-proven).
// ---------------------------------------------------------------------------
__global__ __launch_bounds__(512) void fwd_dft(const float* __restrict__ x,
                                               f16* __restrict__ Sp) {
  __shared__ __align__(16) char lds[3 * 16384];  // 3 slots x (8K x + 8K T)
  const int t    = threadIdx.x;                  // 0..511
  const int w    = t >> 6;                       // 0..7
  const int lane = t & 63;
  const int rl = lane & 15, hi = lane >> 4;
  const int kb = blockIdx.x & (KB_SPLIT - 1);
  const int r0 = (blockIdx.x >> 4) * 64;       // row-block base
  const int k0 = kb * (NPTS / KB_SPLIT);       // 512-wide K range

  // x staging: one chunk per thread, pre-swizzled global source (R17 map)
  const int xr_ = t >> 3;                        // x chunk row (0..63)
  const int xo_ = ((t & 7) ^ (xr_ & 7)) << 2;    // f32 offset in 32-col step
  const float* xs0 = x + (size_t)(r0 + xr_) * NPTS + k0 + xo_;
  const int wu = w * 1024;                     // wave-uniform LDS byte base

  // T compute params: this thread owns chunk t -> (trow = t>>2, cc = t&3),
  // swizzled col-group g = cc ^ (trow&3), data cols g*8..+8 (R7 map).
  const int ttrow = t >> 2, tcc = t & 3;
  const int tg   = tcc ^ (ttrow & 3);
  const int tfreq = ttrow & 63;
  const int tpo   = (ttrow < 64) ? 0 : 6144;     // cos vs sin phase offset

  auto STAGE_X = [&](int kt, int slot) {
    gload16(xs0 + kt * 32, lds + slot * 16384 + wu);
  };
  auto STAGE_T = [&](int kt, int slot) {
    char* tb = lds + slot * 16384 + 8192;
    const int nb = k0 + kt * 32 + tg * 8;
    f16x8 v;
#pragma unroll
    for (int e = 0; e < 8; ++e) v[e] = trig_elem(tfreq, tpo, nb + e);
    *(f16x8*)(tb + t * 16) = v;
  };

  f32x4 acc[4];
#pragma unroll
  for (int i = 0; i < 4; ++i) acc[i] = (f32x4){0.f, 0.f, 0.f, 0.f};

  // swizzled read offsets (lane-constant across kt) — R17 wave split
  const int h  = w >> 1;        // row quarter (0..3)
  const int cg = w & 1;         // col half (64 cols)
  const int axr = h * 16 + rl;  // x_tile row for this lane's A fragment
  const int ad0 = (axr * 8 + ((2 * hi) ^ (axr & 7))) * 16;
  const int ad1 = (axr * 8 + ((2 * hi + 1) ^ (axr & 7))) * 16;
  int bd[4];
#pragma unroll
  for (int s = 0; s < 4; ++s) {
    int trow = cg * 64 + s * 16 + rl;
    bd[s] = (trow * 4 + (hi ^ (trow & 3))) * 16;
  }

  auto COMPUTE = [&](int slot) {
    char* xb = lds + slot * 16384;
    char* tb = xb + 8192;
    f32x4 a0 = *(const f32x4*)(xb + ad0);
    f32x4 a1 = *(const f32x4*)(xb + ad1);
    f16x8 af;
#pragma unroll
    for (int j = 0; j < 4; ++j) { af[j] = (f16)a0[j]; af[4 + j] = (f16)a1[j]; }
#pragma unroll
    for (int s = 0; s < 4; ++s) {
      f16x8 bf = *(const f16x8*)(tb + bd[s]);
      acc[s] = __builtin_amdgcn_mfma_f32_16x16x32_f16(af, bf, acc[s], 0, 0, 0);
    }
  };

  STAGE_X(0, 0); STAGE_T(0, 0);
  STAGE_X(1, 1); STAGE_T(1, 1);
  asm volatile("s_waitcnt vmcnt(1) lgkmcnt(0)" ::: "memory");  // slot0 ready
  __builtin_amdgcn_s_barrier();

  int sc = 0, ss = 2;  // compute slot, stage slot
  for (int kt = 0; kt < 16; ++kt) {
    if (kt + 2 < 16) { STAGE_X(kt + 2, ss); STAGE_T(kt + 2, ss); }
    COMPUTE(sc);
    if (kt < 15) {
      // x-loads outstanding: slots kt+1, kt+2 -> need kt+1 landed
      if (kt + 2 < 16)
        asm volatile("s_waitcnt vmcnt(1) lgkmcnt(0)" ::: "memory");
      else
        asm volatile("s_waitcnt vmcnt(0) lgkmcnt(0)" ::: "memory");
      __builtin_amdgcn_s_barrier();
    }
    sc = (sc == 2) ? 0 : sc + 1;
    ss = (ss == 2) ? 0 : ss + 1;
  }

  // epilogue: wave owns rows r0+h*16..+16, cols cg*64..+64
  f16* out = Sp + ((size_t)kb * ROWS + r0 + h * 16) * 128 + cg * 64;
#pragma unroll
  for (int s = 0; s < 4; ++s)
#pragma unroll
    for (int i = 0; i < 4; ++i)
      out[(hi * 4 + i) * 128 + s * 16 + rl] = (f16)acc[s][i];
}

// ---------------------------------------------------------------------------
// Kernel 2a: split-K partial reduction, f16 in / f32 out (R15-proven).
// ---------------------------------------------------------------------------
__global__ __launch_bounds__(256) void reduce_k(const f16* __restrict__ Sp,
                                                float* __restrict__ Sred) {
  const int idx = blockIdx.x * 256 + threadIdx.x;      // 0..65535 f16x4 idx
  const f16x4* src = (const f16x4*)Sp;
  f32x4 acc = (f32x4){0.f, 0.f, 0.f, 0.f};
#pragma unroll
  for (int s = 0; s < KB_SPLIT; ++s) {
    f16x4 v = src[(size_t)s * (ROWS * 128 / 4) + idx];
#pragma unroll
    for (int e = 0; e < 4; ++e) acc[e] += (float)v[e];
  }
  ((f32x4*)Sred)[idx] = acc;
}

// ---------------------------------------------------------------------------
// Kernel 2b: channel mix + scaling -> Qh (f16).  Grid: 32 batches x 16 o-groups.
// (R13/R15-proven structure, unchanged)
// ---------------------------------------------------------------------------
__global__ __launch_bounds__(256) void mix3(const float* __restrict__ Sred,
                                            const float* __restrict__ Ur,
                                            const float* __restrict__ Ui,
                                            const float* __restrict__ Vr,
                                            const float* __restrict__ Vi,
                                            const float* __restrict__ Sv,
                                            f16* __restrict__ Qh) {
  __shared__ float Srs[64][64], Sis[64][64];
  __shared__ float wr_s[64][4], wi_s[64][4];
  const int b  = blockIdx.x >> 4;
  const int og = blockIdx.x & 15;
  const int t  = threadIdx.x;

#pragma unroll
  for (int j = 0; j < 8; ++j) {
    int f4 = t + 256 * j;                // 0..2047 float4s
    int i = f4 >> 5, kc = (f4 & 31) * 4; // row i, col kc..kc+3
    f32x4 v = *(const f32x4*)(Sred + ((size_t)(b * 64 + i)) * 128 + kc);
    if (kc < 64) *(f32x4*)&Srs[i][kc] = v;
    else         *(f32x4*)&Sis[i][kc - 64] = v;
  }

  {
    int i = t >> 2, ol = t & 3, o = og * 4 + ol;
    float wr = 0.f, wi = 0.f;
#pragma unroll
    for (int r = 0; r < RANKK; ++r) {
      float ur = Ur[i * RANKK + r], ui = Ui[i * RANKK + r];
      float vr = Vr[r * COUT + o],  vi = Vi[r * COUT + o];
      float s = Sv[r];
      wr += s * (ur * vr - ui * vi);
      wi += s * (ur * vi + ui * vr);
    }
    wr_s[i][ol] = wr;
    wi_s[i][ol] = wi;
  }
  __syncthreads();

  const int ol = t >> 6, k = t & 63, o = og * 4 + ol;
  float qr = 0.f, qi = 0.f;
#pragma unroll 4
  for (int i = 0; i < 64; ++i) {
    float sr = Srs[i][k], si = Sis[i][k];     // stride-1 across lanes: conflict-free
    float wr = wr_s[i][ol], wi = wi_s[i][ol]; // wave-uniform broadcast
    qr += sr * wr + si * wi;
    qi += sr * wi - si * wr;
  }
  float sk = (k == 0 ? 1.0f : 2.0f) / (float)NPTS;  // c_k and both ortho 1/sqrt(N)
  f16* qrow = Qh + ((size_t)(b * 64 + o)) * 128;
  qrow[k]      = (f16)(qr * sk);
  qrow[64 + k] = (f16)(-qi * sk);
}

// ---------------------------------------------------------------------------
// Kernel 3: inverse GEMM, block-tiled, computed-in-LDS B tile (no Tt buffer).
//   y[row][n] = sum_c Qh[row][c] * Tt[n][c],  Tt[n][c] = table(c, n)
// Grid = 32 row-blocks x 128 n-blocks. Block: 4 waves, tile 64 rows x 64 n.
// Bt computed once per block (32 cos/thread) into padded LDS; rest is the
// R9/R13/R15-proven structure (plain reads, padded transpose epilogue).
// ---------------------------------------------------------------------------
__global__ __launch_bounds__(256) void inv_dft(const f16* __restrict__ Qh,
                                               float* __restrict__ y) {
  __shared__ f16   Bt[64][136];    // 64 n-rows x 128 k  (+8 f16 pad)
  __shared__ float Tr[4][16][68];  // per-wave store transpose (+4 pad)
  const int t = threadIdx.x, w = t >> 6, lane = t & 63;
  const int rl = lane & 15, hi = lane >> 4;
  const int nb = blockIdx.x & 127;   // n-block (64 wide)
  const int rb = blockIdx.x >> 7;    // row-block (64 rows)
  const int n0 = nb * 64, r0 = rb * 64;

  // A fragments: rows r0 + w*16 + rl, k = 32*ksv + 8*hi (+j)
  const f16* qrow = Qh + (size_t)(r0 + w * 16 + rl) * 128 + 8 * hi;
  f16x8 af[4];
#pragma unroll
  for (int ksv = 0; ksv < 4; ++ksv) af[ksv] = *(const f16x8*)(qrow + ksv * 32);

  // compute B tile: Bt[row][c] = table(c, n0+row); chunk d = (row=d>>4, q=d&15)
#pragma unroll
  for (int j = 0; j < 4; ++j) {
    int d = j * 256 + t, row = d >> 4, q = d & 15;
    int nn = n0 + row;
    int freq0 = (q & 7) * 8;               // c&63 for e=0
    int po = (q < 8) ? 0 : 6144;           // cos rows vs sin rows
    f16x8 v;
#pragma unroll
    for (int e = 0; e < 8; ++e) v[e] = trig_elem(freq0 + e, po, nn);
    *(f16x8*)(&Bt[row][q * 8]) = v;
  }
  __syncthreads();

  f32x4 acc[4];
#pragma unroll
  for (int i = 0; i < 4; ++i) acc[i] = (f32x4){0.f, 0.f, 0.f, 0.f};

#pragma unroll
  for (int ksv = 0; ksv < 4; ++ksv)
#pragma unroll
    for (int s = 0; s < 4; ++s) {
      f16x8 bf = *(const f16x8*)(&Bt[s * 16 + rl][(ksv * 4 + hi) * 8]);
      acc[s] = __builtin_amdgcn_mfma_f32_16x16x32_f16(af[ksv], bf, acc[s], 0, 0, 0);
    }

  // epilogue: per-wave transpose in padded LDS, then coalesced float4 stores.
#pragma unroll
  for (int s = 0; s < 4; ++s)
#pragma unroll
    for (int i = 0; i < 4; ++i)
      Tr[w][hi * 4 + i][s * 16 + rl] = acc[s][i];
#pragma unroll
  for (int p = 0; p < 4; ++p) {
    int r = p * 4 + hi;
    f32x4 v = *(const f32x4*)(&Tr[w][r][rl * 4]);
    *(f32x4*)(y + (size_t)(r0 + w * 16 + r) * NPTS + n0 + rl * 4) = v;
  }
}

// ---------------------------------------------------------------------------
extern "C" void kernel_launch(void* const* d_in, const int* in_sizes, int n_in,
                              void* d_out, int out_size, void* d_ws, size_t ws_size,
                              hipStream_t stream) {
  const float* x  = (const float*)d_in[0];
  const float* Ur = (const float*)d_in[1];
  const float* Ui = (const float*)d_in[2];
  const float* Vr = (const float*)d_in[3];
  const float* Vi = (const float*)d_in[4];
  const float* Sv = (const float*)d_in[5];
  float* y = (float*)d_out;
  char* ws = (char*)d_ws;

  // workspace layout (9.5 MiB total):
  f16*   Sp   = (f16*)ws;                              // KB_SPLIT * 512 KiB = 8 MiB
  char*  p    = ws + (size_t)KB_SPLIT * ROWS * 128 * 2;
  float* Sred = (float*)p;                             // 1 MiB
  f16*   Qh   = (f16*)(p + (size_t)ROWS * 128 * 4);    // 512 KiB

  fwd_dft<<<(ROWS / 64) * KB_SPLIT, 512, 0, stream>>>(x, Sp);
  reduce_k<<<ROWS * 128 / 4 / 256, 256, 0, stream>>>(Sp, Sred);
  mix3<<<BATCH * 16, 256, 0, stream>>>(Sred, Ur, Ui, Vr, Vi, Sv, Qh);
  inv_dft<<<(ROWS / 64) * (NPTS / 64), 256, 0, stream>>>(Qh, y);
}